// Round 5
// baseline (643.542 us; speedup 1.0000x reference)
//
#include <hip/hip_runtime.h>
#include <hip/hip_bf16.h>

#define NN 10000
#define EE 320000
#define EALL (EE + NN)   // 330000 edges incl. self loops
#define BG 64
#define AOUT 1024

typedef __hip_bfloat16 bf16;

// ================= utility =================
__global__ void k_zero_i(int* p, int n) { int i = blockIdx.x * 256 + threadIdx.x; if (i < n) p[i] = 0; }
__global__ void k_zero_f(float* p, int n) { int i = blockIdx.x * 256 + threadIdx.x; if (i < n) p[i] = 0.f; }

// ================= dtype detection =================
// flags: [0] float dtype (1=fp32 storage, 0=bf16); [1] int dtype (1=int32, 0=int64)
//        [2] nan-pattern half count; [3] zero-even-half count
__global__ void k_detect_f(const unsigned short* __restrict__ x, int nhalf,
                           int* __restrict__ nanhits, int* __restrict__ zeroeven) {
    int i = blockIdx.x * 256 + threadIdx.x;
    bool nanp = false, zp = false;
    if (i < nhalf) {
        unsigned short h = x[i];
        nanp = (h & 0x7F80u) == 0x7F80u;
        zp = ((i & 1) == 0) && (h == 0);
    }
    unsigned long long bn = __ballot(nanp);
    unsigned long long bz = __ballot(zp);
    if ((threadIdx.x & 63) == 0) {
        if (bn) atomicAdd(nanhits, __popcll(bn));
        if (bz) atomicAdd(zeroeven, __popcll(bz));
    }
}

__global__ void k_decide(int* flags) {
    flags[0] = (flags[2] > 0 || flags[3] > 100000) ? 1 : 0;
}

__global__ void k_detect_i(const unsigned int* __restrict__ w, int npairs, int* __restrict__ flag) {
    int i = blockIdx.x * 256 + threadIdx.x;
    if (i >= npairs) return;
    if (w[2 * i + 1] != 0u) atomicOr(flag, 1);
}

__global__ void k_cvt_f(const void* __restrict__ src, float* __restrict__ dst, int n,
                        const int* __restrict__ flag) {
    int i = blockIdx.x * 256 + threadIdx.x;
    if (i >= n) return;
    dst[i] = (*flag) ? ((const float*)src)[i] : __bfloat162float(((const bf16*)src)[i]);
}

__global__ void k_cvt_i(const void* __restrict__ src, int* __restrict__ dst, int n,
                        const int* __restrict__ flag) {
    int i = blockIdx.x * 256 + threadIdx.x;
    if (i >= n) return;
    dst[i] = (*flag) ? ((const int*)src)[i] : (int)((const long long*)src)[i];
}

// ================= CSR build (sort edges by dst) =================
__global__ void k_hist(const int* __restrict__ ei, int* __restrict__ deg) {
    int e = blockIdx.x * 256 + threadIdx.x;
    if (e >= EALL) return;
    int dst = (e < EE) ? ei[EE + e] : (e - EE);
    atomicAdd(&deg[dst], 1);
}

__global__ void k_scan(const int* __restrict__ deg, int* __restrict__ rowstart, int* __restrict__ cursor) {
    __shared__ int part[1024];
    const int t = threadIdx.x;
    const int base = t * 10;
    int local[10];
    int s = 0;
    for (int i = 0; i < 10; i++) {
        int idx = base + i;
        int v = (idx < NN) ? deg[idx] : 0;
        local[i] = s; s += v;
    }
    part[t] = s; __syncthreads();
    for (int off = 1; off < 1024; off <<= 1) {
        int v = (t >= off) ? part[t - off] : 0;
        __syncthreads();
        part[t] += v;
        __syncthreads();
    }
    int pre = (t == 0) ? 0 : part[t - 1];
    for (int i = 0; i < 10; i++) {
        int idx = base + i;
        if (idx < NN) { int v = pre + local[i]; rowstart[idx] = v; cursor[idx] = v; }
    }
    if (t == 1023) rowstart[NN] = part[1023];
}

__global__ void k_scatter(const int* __restrict__ ei, int* __restrict__ cursor, int* __restrict__ ssrc) {
    int e = blockIdx.x * 256 + threadIdx.x;
    if (e >= EALL) return;
    int src, dst;
    if (e < EE) { src = ei[e]; dst = ei[EE + e]; }
    else { src = e - EE; dst = src; }
    int pos = atomicAdd(&cursor[dst], 1);
    ssrc[pos] = src;
}

// ================= Linear: C[N,M] = A[N,K] @ W[K,M] (tiled rows in LDS) =================
template<int K, int M, int R>
__global__ __launch_bounds__(1024) void k_linear(const float* __restrict__ A, const float* __restrict__ W,
                                                 float* __restrict__ C) {
    __shared__ float at[R][K];
    const int row0 = blockIdx.x * R;
    const int tid = threadIdx.y * M + threadIdx.x;
    const int nth = M * R;
    for (int i = tid; i < R * K; i += nth) {
        int r = i / K, k = i - r * K;
        int row = row0 + r;
        at[r][k] = (row < NN) ? A[(size_t)row * K + k] : 0.f;
    }
    __syncthreads();
    const int col = threadIdx.x;
    const int r = threadIdx.y;
    float acc0 = 0.f, acc1 = 0.f;
#pragma unroll 8
    for (int k = 0; k < K; k += 2) {
        acc0 += at[r][k]     * W[k * M + col];
        acc1 += at[r][k + 1] * W[(k + 1) * M + col];
    }
    int row = row0 + r;
    if (row < NN) C[(size_t)row * M + col] = acc0 + acc1;
}

// ================= attention terms s,d: one wave per (n,h) =================
template<int H>
__global__ void k_sd(const float* __restrict__ h, const float* __restrict__ asrc,
                     const float* __restrict__ adst, float* __restrict__ sb, float* __restrict__ db) {
    int gw = (blockIdx.x * blockDim.x + threadIdx.x) >> 6;
    int lane = threadIdx.x & 63;
    int n = gw / H, hh = gw - n * H;
    if (n >= NN) return;
    float v = h[(size_t)(n * H + hh) * 64 + lane];
    float ss = v * asrc[hh * 64 + lane];
    float dd = v * adst[hh * 64 + lane];
#pragma unroll
    for (int off = 32; off > 0; off >>= 1) {
        ss += __shfl_down(ss, off);
        dd += __shfl_down(dd, off);
    }
    if (lane == 0) { sb[n * H + hh] = ss; db[n * H + hh] = dd; }
}

// ================= softmax + aggregate per dst node (one block per node) =================
template<int H>
__global__ void k_agg(const float* __restrict__ hbuf, const float* __restrict__ sb,
                      const float* __restrict__ db, const int* __restrict__ rowstart,
                      const int* __restrict__ ssrc, const float* __restrict__ bias,
                      float* __restrict__ out) {
    constexpr int M = H * 64;
    constexpr int LH = (H == 4) ? 2 : 0;
    const int n = blockIdx.x;
    const int tid = threadIdx.x;
    const int start = rowstart[n], end = rowstart[n + 1];
    const int slot = tid >> LH;
    const int hh = tid & (H - 1);
    const int h2 = tid >> 6;
    __shared__ float red[M];
    __shared__ float sm[H], sws[H];
    __shared__ float wl[64 * H];
    __shared__ int srcl[64];
    const float dn = db[n * H + hh];

    float mymax = -3e38f;
    for (int p = start + slot; p < end; p += 64) {
        float e = sb[ssrc[p] * H + hh] + dn;
        e = e > 0.f ? e : 0.2f * e;
        mymax = fmaxf(mymax, e);
    }
    red[tid] = mymax; __syncthreads();
    for (int off = M / 2; off >= H; off >>= 1) {
        if (tid < off) red[tid] = fmaxf(red[tid], red[tid + off]);
        __syncthreads();
    }
    if (tid < H) sm[tid] = red[tid];
    __syncthreads();
    const float mh = sm[hh];

    float wsum = 0.f;
    float acc = 0.f;
    for (int c = start; c < end; c += 64) {
        const int cn = min(64, end - c);
        __syncthreads();
        if (slot < cn) {
            int s = ssrc[c + slot];
            float e = sb[s * H + hh] + dn;
            e = e > 0.f ? e : 0.2f * e;
            float wv = __expf(e - mh);
            wl[slot * H + hh] = wv;
            wsum += wv;
            if (hh == 0) srcl[slot] = s;
        }
        __syncthreads();
        for (int j = 0; j < cn; j++) {
            acc += wl[j * H + h2] * hbuf[(size_t)srcl[j] * M + tid];
        }
    }
    __syncthreads();
    red[tid] = wsum; __syncthreads();
    for (int off = M / 2; off >= H; off >>= 1) {
        if (tid < off) red[tid] += red[tid + off];
        __syncthreads();
    }
    if (tid < H) sws[tid] = red[tid];
    __syncthreads();

    float o = acc / sws[h2] + bias[tid];
    out[(size_t)n * M + tid] = fmaxf(o, 0.f);   // reference applies relu after every GAT layer
}

// ================= global mean pool =================
__global__ void k_pool(const float* __restrict__ feat, const int* __restrict__ batch,
                       float* __restrict__ pooled, float* __restrict__ counts) {
    int n = blockIdx.x;
    int d = threadIdx.x;
    int b = batch[n];
    atomicAdd(&pooled[b * 64 + d], feat[n * 64 + d]);
    if (d == 0) atomicAdd(&counts[b], 1.f);
}

// ================= actor/critic heads =================
__global__ void k_head1(const float* __restrict__ pooled, const float* __restrict__ counts,
                        const float* __restrict__ Wa1, const float* __restrict__ ba1,
                        const float* __restrict__ Wc1, const float* __restrict__ bc1,
                        float* __restrict__ a1, float* __restrict__ c1) {
    __shared__ float p[64];
    int g = blockIdx.x, t = threadIdx.x;
    if (t < 64) p[t] = pooled[g * 64 + t] / fmaxf(counts[g], 1.f);
    __syncthreads();
    int j = t & 63;
    const float* W  = (t < 64) ? Wa1 : Wc1;
    const float* bb = (t < 64) ? ba1 : bc1;
    float acc = 0.f;
#pragma unroll 8
    for (int k = 0; k < 64; k++) acc += p[k] * W[k * 64 + j];
    acc = fmaxf(acc + bb[j], 0.f);
    if (t < 64) a1[g * 64 + j] = acc; else c1[g * 64 + j] = acc;
}

// FP32 OUTPUT — the reference returns float32, so d_out is float*
__global__ __launch_bounds__(1024) void k_head2(const float* __restrict__ a1, const float* __restrict__ c1,
                        const float* __restrict__ Wa2, const float* __restrict__ ba2,
                        const float* __restrict__ Wc2, const float* __restrict__ bc2,
                        float* __restrict__ out) {
    __shared__ float a[64], cc[64];
    int g = blockIdx.x, j = threadIdx.x;
    if (j < 64) a[j] = a1[g * 64 + j];
    else if (j < 128) cc[j - 64] = c1[g * 64 + (j - 64)];
    __syncthreads();
    float acc = 0.f;
#pragma unroll 8
    for (int k = 0; k < 64; k++) acc += a[k] * Wa2[k * AOUT + j];
    out[g * AOUT + j] = tanhf(acc + ba2[j]);
    if (j == 0) {
        float v = 0.f;
        for (int k = 0; k < 64; k++) v += cc[k] * Wc2[k];
        out[BG * AOUT + g] = v + bc2[0];
    }
}

extern "C" void kernel_launch(void* const* d_in, const int* in_sizes, int n_in,
                              void* d_out, int out_size, void* d_ws, size_t ws_size,
                              hipStream_t stream) {
    float* out = (float*)d_out;

    char* w = (char*)d_ws;
    auto alloc = [&](size_t bytes) { void* p = (void*)w; w += (bytes + 255) & ~size_t(255); return p; };
    float* xf      = (float*)alloc((size_t)NN * 128 * 4);
    int*   ei32    = (int*)alloc((size_t)2 * EE * 4);
    int*   b32     = (int*)alloc((size_t)NN * 4);
    float* bufA    = (float*)alloc((size_t)NN * 256 * 4);
    float* bufB    = (float*)alloc((size_t)NN * 256 * 4);
    float* sb      = (float*)alloc((size_t)NN * 4 * 4);
    float* db      = (float*)alloc((size_t)NN * 4 * 4);
    int*   deg     = (int*)alloc((size_t)NN * 4);
    int*   rowstart= (int*)alloc((size_t)(NN + 1) * 4);
    int*   cursor  = (int*)alloc((size_t)NN * 4);
    int*   ssrc    = (int*)alloc((size_t)EALL * 4);
    float* pooled  = (float*)alloc((size_t)BG * 64 * 4);
    float* counts  = (float*)alloc((size_t)BG * 4);
    float* a1      = (float*)alloc((size_t)BG * 64 * 4);
    float* c1      = (float*)alloc((size_t)BG * 64 * 4);
    int*   flags   = (int*)alloc(64);
    const int wsz[20] = {32768,256,256,256,65536,256,256,256,16384,64,64,64,4096,64,65536,1024,4096,64,64,1};
    float* wbuf[20];
    for (int s = 0; s < 20; s++) wbuf[s] = (float*)alloc((size_t)wsz[s] * 4);

    // ---- detect dtypes + normalize inputs ----
    k_zero_i<<<1, 64, 0, stream>>>(flags, 4);
    k_detect_f<<<(NN * 128 + 255) / 256, 256, 0, stream>>>((const unsigned short*)d_in[0], NN * 128, &flags[2], &flags[3]);
    k_detect_i<<<(EE + 255) / 256, 256, 0, stream>>>((const unsigned int*)d_in[1], EE, &flags[1]);
    k_decide<<<1, 1, 0, stream>>>(flags);
    k_cvt_f<<<(NN * 128 + 255) / 256, 256, 0, stream>>>(d_in[0], xf, NN * 128, &flags[0]);
    for (int s = 0; s < 20; s++)
        k_cvt_f<<<(wsz[s] + 255) / 256, 256, 0, stream>>>(d_in[3 + s], wbuf[s], wsz[s], &flags[0]);
    k_cvt_i<<<(2 * EE + 255) / 256, 256, 0, stream>>>(d_in[1], ei32, 2 * EE, &flags[1]);
    k_cvt_i<<<(NN + 255) / 256, 256, 0, stream>>>(d_in[2], b32, NN, &flags[1]);

    const float *W1f = wbuf[0], *as1f = wbuf[1], *ad1f = wbuf[2], *b1f = wbuf[3];
    const float *W2f = wbuf[4], *as2f = wbuf[5], *ad2f = wbuf[6], *b2f = wbuf[7];
    const float *W3f = wbuf[8], *as3f = wbuf[9], *ad3f = wbuf[10], *b3f = wbuf[11];
    const float *Wa1f = wbuf[12], *ba1f = wbuf[13], *Wa2f = wbuf[14], *ba2f = wbuf[15];
    const float *Wc1f = wbuf[16], *bc1f = wbuf[17], *Wc2f = wbuf[18], *bc2f = wbuf[19];

    // ---- CSR build (shared across the 3 layers) ----
    k_zero_i<<<(NN + 255) / 256, 256, 0, stream>>>(deg, NN);
    k_hist<<<(EALL + 255) / 256, 256, 0, stream>>>(ei32, deg);
    k_scan<<<1, 1024, 0, stream>>>(deg, rowstart, cursor);
    k_scatter<<<(EALL + 255) / 256, 256, 0, stream>>>(ei32, cursor, ssrc);

    // ---- Layer 1: in 128, heads=4, out 64, concat ----
    k_linear<128, 256, 4><<<(NN + 3) / 4, dim3(256, 4), 0, stream>>>(xf, W1f, bufA);
    k_sd<4><<<NN, 256, 0, stream>>>(bufA, as1f, ad1f, sb, db);
    k_agg<4><<<NN, 256, 0, stream>>>(bufA, sb, db, rowstart, ssrc, b1f, bufB);

    // ---- Layer 2: in 256, heads=4, out 64, concat ----
    k_linear<256, 256, 4><<<(NN + 3) / 4, dim3(256, 4), 0, stream>>>(bufB, W2f, bufA);
    k_sd<4><<<NN, 256, 0, stream>>>(bufA, as2f, ad2f, sb, db);
    k_agg<4><<<NN, 256, 0, stream>>>(bufA, sb, db, rowstart, ssrc, b2f, bufB);

    // ---- Layer 3: in 256, heads=1, out 64 ----
    k_linear<256, 64, 16><<<(NN + 15) / 16, dim3(64, 16), 0, stream>>>(bufB, W3f, bufA);
    k_sd<1><<<(NN + 3) / 4, 256, 0, stream>>>(bufA, as3f, ad3f, sb, db);
    k_agg<1><<<NN, 64, 0, stream>>>(bufA, sb, db, rowstart, ssrc, b3f, bufB);

    // ---- global mean pool ----
    k_zero_f<<<(BG * 64 + 255) / 256, 256, 0, stream>>>(pooled, BG * 64);
    k_zero_f<<<1, 256, 0, stream>>>(counts, BG);
    k_pool<<<NN, 64, 0, stream>>>(bufB, b32, pooled, counts);

    // ---- heads ----
    k_head1<<<BG, 128, 0, stream>>>(pooled, counts, Wa1f, ba1f, Wc1f, bc1f, a1, c1);
    k_head2<<<BG, 1024, 0, stream>>>(a1, c1, Wa2f, ba2f, Wc2f, bc2f, out);
}

// Round 6
// 539.988 us; speedup vs baseline: 1.1918x; 1.1918x over previous
//
#include <hip/hip_runtime.h>
#include <hip/hip_bf16.h>

#define NN 10000
#define EE 320000
#define EALL (EE + NN)   // 330000 edges incl. self loops
#define BG 64
#define AOUT 1024

typedef __hip_bfloat16 bf16;

// ================= utility =================
__global__ void k_zero_i(int* p, int n) { int i = blockIdx.x * 256 + threadIdx.x; if (i < n) p[i] = 0; }
__global__ void k_zero_f(float* p, int n) { int i = blockIdx.x * 256 + threadIdx.x; if (i < n) p[i] = 0.f; }

// ================= dtype detection =================
// flags: [0] float dtype (1=fp32 storage, 0=bf16); [1] int dtype (1=int32, 0=int64)
//        [2] nan-pattern half count; [3] zero-even-half count
__global__ void k_detect_f(const unsigned short* __restrict__ x, int nhalf,
                           int* __restrict__ nanhits, int* __restrict__ zeroeven) {
    int i = blockIdx.x * 256 + threadIdx.x;
    bool nanp = false, zp = false;
    if (i < nhalf) {
        unsigned short h = x[i];
        nanp = (h & 0x7F80u) == 0x7F80u;
        zp = ((i & 1) == 0) && (h == 0);
    }
    unsigned long long bn = __ballot(nanp);
    unsigned long long bz = __ballot(zp);
    if ((threadIdx.x & 63) == 0) {
        if (bn) atomicAdd(nanhits, __popcll(bn));
        if (bz) atomicAdd(zeroeven, __popcll(bz));
    }
}

__global__ void k_decide(int* flags) {
    flags[0] = (flags[2] > 0 || flags[3] > 100000) ? 1 : 0;
}

__global__ void k_detect_i(const unsigned int* __restrict__ w, int npairs, int* __restrict__ flag) {
    int i = blockIdx.x * 256 + threadIdx.x;
    if (i >= npairs) return;
    if (w[2 * i + 1] != 0u) atomicOr(flag, 1);
}

__global__ void k_cvt_f(const void* __restrict__ src, float* __restrict__ dst, int n,
                        const int* __restrict__ flag) {
    int i = blockIdx.x * 256 + threadIdx.x;
    if (i >= n) return;
    dst[i] = (*flag) ? ((const float*)src)[i] : __bfloat162float(((const bf16*)src)[i]);
}

__global__ void k_cvt_i(const void* __restrict__ src, int* __restrict__ dst, int n,
                        const int* __restrict__ flag) {
    int i = blockIdx.x * 256 + threadIdx.x;
    if (i >= n) return;
    dst[i] = (*flag) ? ((const int*)src)[i] : (int)((const long long*)src)[i];
}

// packed weight conversion: 20 tensors in one launch (layout proven by R2/R3 bit-identical runs)
struct WPtrs { const void* p[20]; };
#define WTOT 191361
__global__ void k_cvt_weights(WPtrs ptrs, float* __restrict__ dst, const int* __restrict__ flag) {
    const int sz[20] = {32768,256,256,256,65536,256,256,256,16384,64,64,64,4096,64,65536,1024,4096,64,64,1};
    int i = blockIdx.x * 256 + threadIdx.x;
    if (i >= WTOT) return;
    int seg = 0, off = 0;
    while (i - off >= sz[seg]) { off += sz[seg]; seg++; }
    const void* src = ptrs.p[seg];
    int j = i - off;
    dst[i] = (*flag) ? ((const float*)src)[j] : __bfloat162float(((const bf16*)src)[j]);
}

// ================= CSR build (sort edges by dst) =================
__global__ void k_hist(const int* __restrict__ ei, int* __restrict__ deg) {
    int e = blockIdx.x * 256 + threadIdx.x;
    if (e >= EALL) return;
    int dst = (e < EE) ? ei[EE + e] : (e - EE);
    atomicAdd(&deg[dst], 1);
}

__global__ void k_scan(const int* __restrict__ deg, int* __restrict__ rowstart, int* __restrict__ cursor) {
    __shared__ int part[1024];
    const int t = threadIdx.x;
    const int base = t * 10;
    int local[10];
    int s = 0;
    for (int i = 0; i < 10; i++) {
        int idx = base + i;
        int v = (idx < NN) ? deg[idx] : 0;
        local[i] = s; s += v;
    }
    part[t] = s; __syncthreads();
    for (int off = 1; off < 1024; off <<= 1) {
        int v = (t >= off) ? part[t - off] : 0;
        __syncthreads();
        part[t] += v;
        __syncthreads();
    }
    int pre = (t == 0) ? 0 : part[t - 1];
    for (int i = 0; i < 10; i++) {
        int idx = base + i;
        if (idx < NN) { int v = pre + local[i]; rowstart[idx] = v; cursor[idx] = v; }
    }
    if (t == 1023) rowstart[NN] = part[1023];
}

__global__ void k_scatter(const int* __restrict__ ei, int* __restrict__ cursor, int* __restrict__ ssrc) {
    int e = blockIdx.x * 256 + threadIdx.x;
    if (e >= EALL) return;
    int src, dst;
    if (e < EE) { src = ei[e]; dst = ei[EE + e]; }
    else { src = e - EE; dst = src; }
    int pos = atomicAdd(&cursor[dst], 1);
    ssrc[pos] = src;
}

// ================= GEMM: C[N,M] = A[N,K] @ W[K,M], 64x64 tile, 4x4/thread =================
template<int K, int M>
__global__ __launch_bounds__(256) void k_gemm(const float* __restrict__ A, const float* __restrict__ W,
                                              float* __restrict__ C) {
    constexpr int BK = 32;
    __shared__ float At[BK][68];   // A transposed tile, pad 68 (17*16B) for alignment + banks
    __shared__ float Wt[BK][64];
    const int row0 = blockIdx.x * 64;
    const int col0 = blockIdx.y * 64;
    const int t = threadIdx.x;
    const int tx = t & 15, ty = t >> 4;
    float acc[4][4] = {};

    for (int k0 = 0; k0 < K; k0 += BK) {
        {
            const int kk = t & 31;
            const int rbase = t >> 5;
#pragma unroll
            for (int j = 0; j < 8; j++) {
                int r = rbase + j * 8;
                int row = row0 + r;
                At[kk][r] = (row < NN) ? A[(size_t)row * K + k0 + kk] : 0.f;
            }
            const int cc = t & 63;
            const int kbase = t >> 6;
#pragma unroll
            for (int j = 0; j < 8; j++) {
                int kk2 = kbase + j * 4;
                Wt[kk2][cc] = W[(size_t)(k0 + kk2) * M + col0 + cc];
            }
        }
        __syncthreads();
#pragma unroll
        for (int k = 0; k < BK; k++) {
            float4 a4 = *(const float4*)&At[k][ty * 4];
            float4 w4 = *(const float4*)&Wt[k][tx * 4];
            float av[4] = {a4.x, a4.y, a4.z, a4.w};
            float wv[4] = {w4.x, w4.y, w4.z, w4.w};
#pragma unroll
            for (int m = 0; m < 4; m++)
#pragma unroll
                for (int n = 0; n < 4; n++)
                    acc[m][n] += av[m] * wv[n];
        }
        __syncthreads();
    }
#pragma unroll
    for (int m = 0; m < 4; m++) {
        int row = row0 + ty * 4 + m;
        if (row < NN) {
            float4 v = make_float4(acc[m][0], acc[m][1], acc[m][2], acc[m][3]);
            *(float4*)&C[(size_t)row * M + col0 + tx * 4] = v;
        }
    }
}

// ================= attention terms s,d: one wave per (n,h) =================
template<int H>
__global__ void k_sd(const float* __restrict__ h, const float* __restrict__ asrc,
                     const float* __restrict__ adst, float* __restrict__ sb, float* __restrict__ db) {
    int gw = (blockIdx.x * blockDim.x + threadIdx.x) >> 6;
    int lane = threadIdx.x & 63;
    int n = gw / H, hh = gw - n * H;
    if (n >= NN) return;
    float v = h[(size_t)(n * H + hh) * 64 + lane];
    float ss = v * asrc[hh * 64 + lane];
    float dd = v * adst[hh * 64 + lane];
#pragma unroll
    for (int off = 32; off > 0; off >>= 1) {
        ss += __shfl_down(ss, off);
        dd += __shfl_down(dd, off);
    }
    if (lane == 0) { sb[n * H + hh] = ss; db[n * H + hh] = dd; }
}

// ================= softmax + aggregate per dst node (one block per node) =================
template<int H>
__global__ void k_agg(const float* __restrict__ hbuf, const float* __restrict__ sb,
                      const float* __restrict__ db, const int* __restrict__ rowstart,
                      const int* __restrict__ ssrc, const float* __restrict__ bias,
                      float* __restrict__ out) {
    constexpr int M = H * 64;
    constexpr int LH = (H == 4) ? 2 : 0;
    const int n = blockIdx.x;
    const int tid = threadIdx.x;
    const int start = rowstart[n], end = rowstart[n + 1];
    const int slot = tid >> LH;
    const int hh = tid & (H - 1);
    const int h2 = tid >> 6;
    __shared__ float red[M];
    __shared__ float sm[H], sws[H];
    __shared__ float wl[64 * H];
    __shared__ int srcl[64];
    const float dn = db[n * H + hh];

    float mymax = -3e38f;
    for (int p = start + slot; p < end; p += 64) {
        float e = sb[ssrc[p] * H + hh] + dn;
        e = e > 0.f ? e : 0.2f * e;
        mymax = fmaxf(mymax, e);
    }
    red[tid] = mymax; __syncthreads();
    for (int off = M / 2; off >= H; off >>= 1) {
        if (tid < off) red[tid] = fmaxf(red[tid], red[tid + off]);
        __syncthreads();
    }
    if (tid < H) sm[tid] = red[tid];
    __syncthreads();
    const float mh = sm[hh];

    float wsum = 0.f;
    float acc = 0.f;
    for (int c = start; c < end; c += 64) {
        const int cn = min(64, end - c);
        __syncthreads();
        if (slot < cn) {
            int s = ssrc[c + slot];
            float e = sb[s * H + hh] + dn;
            e = e > 0.f ? e : 0.2f * e;
            float wv = __expf(e - mh);
            wl[slot * H + hh] = wv;
            wsum += wv;
            if (hh == 0) srcl[slot] = s;
        }
        __syncthreads();
        for (int j = 0; j < cn; j++) {
            acc += wl[j * H + h2] * hbuf[(size_t)srcl[j] * M + tid];
        }
    }
    __syncthreads();
    red[tid] = wsum; __syncthreads();
    for (int off = M / 2; off >= H; off >>= 1) {
        if (tid < off) red[tid] += red[tid + off];
        __syncthreads();
    }
    if (tid < H) sws[tid] = red[tid];
    __syncthreads();

    float o = acc / sws[h2] + bias[tid];
    out[(size_t)n * M + tid] = fmaxf(o, 0.f);   // reference applies relu after every GAT layer
}

// ================= global mean pool =================
__global__ void k_pool(const float* __restrict__ feat, const int* __restrict__ batch,
                       float* __restrict__ pooled, float* __restrict__ counts) {
    int n = blockIdx.x;
    int d = threadIdx.x;
    int b = batch[n];
    atomicAdd(&pooled[b * 64 + d], feat[n * 64 + d]);
    if (d == 0) atomicAdd(&counts[b], 1.f);
}

// ================= actor/critic heads =================
__global__ void k_head1(const float* __restrict__ pooled, const float* __restrict__ counts,
                        const float* __restrict__ Wa1, const float* __restrict__ ba1,
                        const float* __restrict__ Wc1, const float* __restrict__ bc1,
                        float* __restrict__ a1, float* __restrict__ c1) {
    __shared__ float p[64];
    int g = blockIdx.x, t = threadIdx.x;
    if (t < 64) p[t] = pooled[g * 64 + t] / fmaxf(counts[g], 1.f);
    __syncthreads();
    int j = t & 63;
    const float* W  = (t < 64) ? Wa1 : Wc1;
    const float* bb = (t < 64) ? ba1 : bc1;
    float acc = 0.f;
#pragma unroll 8
    for (int k = 0; k < 64; k++) acc += p[k] * W[k * 64 + j];
    acc = fmaxf(acc + bb[j], 0.f);
    if (t < 64) a1[g * 64 + j] = acc; else c1[g * 64 + j] = acc;
}

// FP32 OUTPUT — the reference returns float32, so d_out is float*
__global__ __launch_bounds__(1024) void k_head2(const float* __restrict__ a1, const float* __restrict__ c1,
                        const float* __restrict__ Wa2, const float* __restrict__ ba2,
                        const float* __restrict__ Wc2, const float* __restrict__ bc2,
                        float* __restrict__ out) {
    __shared__ float a[64], cc[64];
    int g = blockIdx.x, j = threadIdx.x;
    if (j < 64) a[j] = a1[g * 64 + j];
    else if (j < 128) cc[j - 64] = c1[g * 64 + (j - 64)];
    __syncthreads();
    float acc = 0.f;
#pragma unroll 8
    for (int k = 0; k < 64; k++) acc += a[k] * Wa2[k * AOUT + j];
    out[g * AOUT + j] = tanhf(acc + ba2[j]);
    if (j == 0) {
        float v = 0.f;
        for (int k = 0; k < 64; k++) v += cc[k] * Wc2[k];
        out[BG * AOUT + g] = v + bc2[0];
    }
}

extern "C" void kernel_launch(void* const* d_in, const int* in_sizes, int n_in,
                              void* d_out, int out_size, void* d_ws, size_t ws_size,
                              hipStream_t stream) {
    float* out = (float*)d_out;

    char* w = (char*)d_ws;
    auto alloc = [&](size_t bytes) { void* p = (void*)w; w += (bytes + 255) & ~size_t(255); return p; };
    float* xf      = (float*)alloc((size_t)NN * 128 * 4);
    float* wf      = (float*)alloc((size_t)WTOT * 4);
    int*   ei32    = (int*)alloc((size_t)2 * EE * 4);
    int*   b32     = (int*)alloc((size_t)NN * 4);
    float* bufA    = (float*)alloc((size_t)NN * 256 * 4);
    float* bufB    = (float*)alloc((size_t)NN * 256 * 4);
    float* sb      = (float*)alloc((size_t)NN * 4 * 4);
    float* db      = (float*)alloc((size_t)NN * 4 * 4);
    int*   deg     = (int*)alloc((size_t)NN * 4);
    int*   rowstart= (int*)alloc((size_t)(NN + 1) * 4);
    int*   cursor  = (int*)alloc((size_t)NN * 4);
    int*   ssrc    = (int*)alloc((size_t)EALL * 4);
    float* pooled  = (float*)alloc((size_t)BG * 64 * 4);   // counts allocated right after (contiguous)
    float* counts  = (float*)alloc((size_t)BG * 4);
    float* a1      = (float*)alloc((size_t)BG * 64 * 4);
    float* c1      = (float*)alloc((size_t)BG * 64 * 4);
    int*   flags   = (int*)alloc(64);

    // ---- detect dtypes + normalize inputs ----
    k_zero_i<<<1, 64, 0, stream>>>(flags, 4);
    k_detect_f<<<(NN * 128 + 255) / 256, 256, 0, stream>>>((const unsigned short*)d_in[0], NN * 128, &flags[2], &flags[3]);
    k_detect_i<<<(EE + 255) / 256, 256, 0, stream>>>((const unsigned int*)d_in[1], EE, &flags[1]);
    k_decide<<<1, 1, 0, stream>>>(flags);
    k_cvt_f<<<(NN * 128 + 255) / 256, 256, 0, stream>>>(d_in[0], xf, NN * 128, &flags[0]);
    WPtrs wp;
    for (int s = 0; s < 20; s++) wp.p[s] = d_in[3 + s];
    k_cvt_weights<<<(WTOT + 255) / 256, 256, 0, stream>>>(wp, wf, &flags[0]);
    k_cvt_i<<<(2 * EE + 255) / 256, 256, 0, stream>>>(d_in[1], ei32, 2 * EE, &flags[1]);
    k_cvt_i<<<(NN + 255) / 256, 256, 0, stream>>>(d_in[2], b32, NN, &flags[1]);

    const int wsz[20] = {32768,256,256,256,65536,256,256,256,16384,64,64,64,4096,64,65536,1024,4096,64,64,1};
    int woff[20]; int acc = 0;
    for (int s = 0; s < 20; s++) { woff[s] = acc; acc += wsz[s]; }
    const float *W1f = wf + woff[0], *as1f = wf + woff[1], *ad1f = wf + woff[2], *b1f = wf + woff[3];
    const float *W2f = wf + woff[4], *as2f = wf + woff[5], *ad2f = wf + woff[6], *b2f = wf + woff[7];
    const float *W3f = wf + woff[8], *as3f = wf + woff[9], *ad3f = wf + woff[10], *b3f = wf + woff[11];
    const float *Wa1f = wf + woff[12], *ba1f = wf + woff[13], *Wa2f = wf + woff[14], *ba2f = wf + woff[15];
    const float *Wc1f = wf + woff[16], *bc1f = wf + woff[17], *Wc2f = wf + woff[18], *bc2f = wf + woff[19];

    // ---- CSR build (shared across the 3 layers) ----
    k_zero_i<<<(NN + 255) / 256, 256, 0, stream>>>(deg, NN);
    k_hist<<<(EALL + 255) / 256, 256, 0, stream>>>(ei32, deg);
    k_scan<<<1, 1024, 0, stream>>>(deg, rowstart, cursor);
    k_scatter<<<(EALL + 255) / 256, 256, 0, stream>>>(ei32, cursor, ssrc);

    // ---- Layer 1: in 128, heads=4, out 64, concat ----
    k_gemm<128, 256><<<dim3(157, 4), 256, 0, stream>>>(xf, W1f, bufA);
    k_sd<4><<<NN, 256, 0, stream>>>(bufA, as1f, ad1f, sb, db);
    k_agg<4><<<NN, 256, 0, stream>>>(bufA, sb, db, rowstart, ssrc, b1f, bufB);

    // ---- Layer 2: in 256, heads=4, out 64, concat ----
    k_gemm<256, 256><<<dim3(157, 4), 256, 0, stream>>>(bufB, W2f, bufA);
    k_sd<4><<<NN, 256, 0, stream>>>(bufA, as2f, ad2f, sb, db);
    k_agg<4><<<NN, 256, 0, stream>>>(bufA, sb, db, rowstart, ssrc, b2f, bufB);

    // ---- Layer 3: in 256, heads=1, out 64 ----
    k_gemm<256, 64><<<dim3(157, 1), 256, 0, stream>>>(bufB, W3f, bufA);
    k_sd<1><<<(NN + 3) / 4, 256, 0, stream>>>(bufA, as3f, ad3f, sb, db);
    k_agg<1><<<NN, 64, 0, stream>>>(bufA, sb, db, rowstart, ssrc, b3f, bufB);

    // ---- global mean pool (pooled+counts are contiguous: one zero launch) ----
    k_zero_f<<<(BG * 64 + BG + 255) / 256, 256, 0, stream>>>(pooled, BG * 64 + BG);
    k_pool<<<NN, 64, 0, stream>>>(bufB, b32, pooled, counts);

    // ---- heads ----
    k_head1<<<BG, 128, 0, stream>>>(pooled, counts, Wa1f, ba1f, Wc1f, bc1f, a1, c1);
    k_head2<<<BG, 1024, 0, stream>>>(a1, c1, Wa2f, ba2f, Wc2f, bc2f, out);
}

// Round 7
// 526.655 us; speedup vs baseline: 1.2219x; 1.0253x over previous
//
#include <hip/hip_runtime.h>
#include <hip/hip_bf16.h>

#define NN 10000
#define EE 320000
#define EALL (EE + NN)   // 330000 edges incl. self loops
#define BG 64
#define AOUT 1024

typedef __hip_bfloat16 bf16;

// ================= utility =================
__global__ void k_zero_i(int* p, int n) { int i = blockIdx.x * 256 + threadIdx.x; if (i < n) p[i] = 0; }

// ================= dtype detection =================
// flags: [0] float dtype (1=fp32 storage, 0=bf16); [1] int dtype (1=int32, 0=int64)
//        [2] nan-pattern half count; [3] zero-even-half count
__global__ void k_detect_f(const unsigned short* __restrict__ x, int nhalf,
                           int* __restrict__ nanhits, int* __restrict__ zeroeven) {
    int i = blockIdx.x * 256 + threadIdx.x;
    bool nanp = false, zp = false;
    if (i < nhalf) {
        unsigned short h = x[i];
        nanp = (h & 0x7F80u) == 0x7F80u;
        zp = ((i & 1) == 0) && (h == 0);
    }
    unsigned long long bn = __ballot(nanp);
    unsigned long long bz = __ballot(zp);
    if ((threadIdx.x & 63) == 0) {
        if (bn) atomicAdd(nanhits, __popcll(bn));
        if (bz) atomicAdd(zeroeven, __popcll(bz));
    }
}

__global__ void k_decide(int* flags) {
    flags[0] = (flags[2] > 0 || flags[3] > 100000) ? 1 : 0;
}

__global__ void k_detect_i(const unsigned int* __restrict__ w, int npairs, int* __restrict__ flag) {
    int i = blockIdx.x * 256 + threadIdx.x;
    if (i >= npairs) return;
    if (w[2 * i + 1] != 0u) atomicOr(flag, 1);
}

__global__ void k_cvt_f(const void* __restrict__ src, float* __restrict__ dst, int n,
                        const int* __restrict__ flag) {
    int i = blockIdx.x * 256 + threadIdx.x;
    if (i >= n) return;
    dst[i] = (*flag) ? ((const float*)src)[i] : __bfloat162float(((const bf16*)src)[i]);
}

__global__ void k_cvt_i(const void* __restrict__ src, int* __restrict__ dst, int n,
                        const int* __restrict__ flag) {
    int i = blockIdx.x * 256 + threadIdx.x;
    if (i >= n) return;
    dst[i] = (*flag) ? ((const int*)src)[i] : (int)((const long long*)src)[i];
}

// packed weight conversion: 20 tensors in one launch
struct WPtrs { const void* p[20]; };
#define WTOT 191361
__global__ void k_cvt_weights(WPtrs ptrs, float* __restrict__ dst, const int* __restrict__ flag) {
    const int sz[20] = {32768,256,256,256,65536,256,256,256,16384,64,64,64,4096,64,65536,1024,4096,64,64,1};
    int i = blockIdx.x * 256 + threadIdx.x;
    if (i >= WTOT) return;
    int seg = 0, off = 0;
    while (i - off >= sz[seg]) { off += sz[seg]; seg++; }
    const void* src = ptrs.p[seg];
    int j = i - off;
    dst[i] = (*flag) ? ((const float*)src)[j] : __bfloat162float(((const bf16*)src)[j]);
}

// ================= CSR build (sort edges by dst) =================
__global__ void k_hist(const int* __restrict__ ei, int* __restrict__ deg) {
    int e = blockIdx.x * 256 + threadIdx.x;
    if (e >= EALL) return;
    int dst = (e < EE) ? ei[EE + e] : (e - EE);
    atomicAdd(&deg[dst], 1);
}

__global__ void k_scan(const int* __restrict__ deg, int* __restrict__ rowstart, int* __restrict__ cursor) {
    __shared__ int part[1024];
    const int t = threadIdx.x;
    const int base = t * 10;
    int local[10];
    int s = 0;
    for (int i = 0; i < 10; i++) {
        int idx = base + i;
        int v = (idx < NN) ? deg[idx] : 0;
        local[i] = s; s += v;
    }
    part[t] = s; __syncthreads();
    for (int off = 1; off < 1024; off <<= 1) {
        int v = (t >= off) ? part[t - off] : 0;
        __syncthreads();
        part[t] += v;
        __syncthreads();
    }
    int pre = (t == 0) ? 0 : part[t - 1];
    for (int i = 0; i < 10; i++) {
        int idx = base + i;
        if (idx < NN) { int v = pre + local[i]; rowstart[idx] = v; cursor[idx] = v; }
    }
    if (t == 1023) rowstart[NN] = part[1023];
}

__global__ void k_scatter(const int* __restrict__ ei, int* __restrict__ cursor, int* __restrict__ ssrc) {
    int e = blockIdx.x * 256 + threadIdx.x;
    if (e >= EALL) return;
    int src, dst;
    if (e < EE) { src = ei[e]; dst = ei[EE + e]; }
    else { src = e - EE; dst = src; }
    int pos = atomicAdd(&cursor[dst], 1);
    ssrc[pos] = src;
}

// ================= GEMM: C[N,M] = A[N,K] @ W[K,M], 64x64 tile, 4x4/thread =================
template<int K, int M>
__global__ __launch_bounds__(256) void k_gemm(const float* __restrict__ A, const float* __restrict__ W,
                                              float* __restrict__ C) {
    constexpr int BK = 32;
    __shared__ float At[BK][68];
    __shared__ float Wt[BK][64];
    const int row0 = blockIdx.x * 64;
    const int col0 = blockIdx.y * 64;
    const int t = threadIdx.x;
    const int tx = t & 15, ty = t >> 4;
    float acc[4][4] = {};

    for (int k0 = 0; k0 < K; k0 += BK) {
        {
            const int kk = t & 31;
            const int rbase = t >> 5;
#pragma unroll
            for (int j = 0; j < 8; j++) {
                int r = rbase + j * 8;
                int row = row0 + r;
                At[kk][r] = (row < NN) ? A[(size_t)row * K + k0 + kk] : 0.f;
            }
            const int cc = t & 63;
            const int kbase = t >> 6;
#pragma unroll
            for (int j = 0; j < 8; j++) {
                int kk2 = kbase + j * 4;
                Wt[kk2][cc] = W[(size_t)(k0 + kk2) * M + col0 + cc];
            }
        }
        __syncthreads();
#pragma unroll
        for (int k = 0; k < BK; k++) {
            float4 a4 = *(const float4*)&At[k][ty * 4];
            float4 w4 = *(const float4*)&Wt[k][tx * 4];
            float av[4] = {a4.x, a4.y, a4.z, a4.w};
            float wv[4] = {w4.x, w4.y, w4.z, w4.w};
#pragma unroll
            for (int m = 0; m < 4; m++)
#pragma unroll
                for (int n = 0; n < 4; n++)
                    acc[m][n] += av[m] * wv[n];
        }
        __syncthreads();
    }
#pragma unroll
    for (int m = 0; m < 4; m++) {
        int row = row0 + ty * 4 + m;
        if (row < NN) {
            float4 v = make_float4(acc[m][0], acc[m][1], acc[m][2], acc[m][3]);
            *(float4*)&C[(size_t)row * M + col0 + tx * 4] = v;
        }
    }
}

// ================= attention terms s,d: one wave per (n,h) =================
template<int H>
__global__ void k_sd(const float* __restrict__ h, const float* __restrict__ asrc,
                     const float* __restrict__ adst, float* __restrict__ sb, float* __restrict__ db) {
    int gw = (blockIdx.x * blockDim.x + threadIdx.x) >> 6;
    int lane = threadIdx.x & 63;
    int n = gw / H, hh = gw - n * H;
    if (n >= NN) return;
    float v = h[(size_t)(n * H + hh) * 64 + lane];
    float ss = v * asrc[hh * 64 + lane];
    float dd = v * adst[hh * 64 + lane];
#pragma unroll
    for (int off = 32; off > 0; off >>= 1) {
        ss += __shfl_down(ss, off);
        dd += __shfl_down(dd, off);
    }
    if (lane == 0) { sb[n * H + hh] = ss; db[n * H + hh] = dd; }
}

// ================= softmax + aggregate per dst node (one block per node) =================
template<int H>
__global__ void k_agg(const float* __restrict__ hbuf, const float* __restrict__ sb,
                      const float* __restrict__ db, const int* __restrict__ rowstart,
                      const int* __restrict__ ssrc, const float* __restrict__ bias,
                      float* __restrict__ out) {
    constexpr int M = H * 64;
    constexpr int LH = (H == 4) ? 2 : 0;
    const int n = blockIdx.x;
    const int tid = threadIdx.x;
    const int start = rowstart[n], end = rowstart[n + 1];
    const int slot = tid >> LH;
    const int hh = tid & (H - 1);
    const int h2 = tid >> 6;
    __shared__ float red[M];
    __shared__ float sm[H], sws[H];
    __shared__ float wl[64 * H];
    __shared__ int srcl[64];
    const float dn = db[n * H + hh];

    float mymax = -3e38f;
    for (int p = start + slot; p < end; p += 64) {
        float e = sb[ssrc[p] * H + hh] + dn;
        e = e > 0.f ? e : 0.2f * e;
        mymax = fmaxf(mymax, e);
    }
    red[tid] = mymax; __syncthreads();
    for (int off = M / 2; off >= H; off >>= 1) {
        if (tid < off) red[tid] = fmaxf(red[tid], red[tid + off]);
        __syncthreads();
    }
    if (tid < H) sm[tid] = red[tid];
    __syncthreads();
    const float mh = sm[hh];

    float wsum = 0.f;
    float acc = 0.f;
    for (int c = start; c < end; c += 64) {
        const int cn = min(64, end - c);
        __syncthreads();
        if (slot < cn) {
            int s = ssrc[c + slot];
            float e = sb[s * H + hh] + dn;
            e = e > 0.f ? e : 0.2f * e;
            float wv = __expf(e - mh);
            wl[slot * H + hh] = wv;
            wsum += wv;
            if (hh == 0) srcl[slot] = s;
        }
        __syncthreads();
        for (int j = 0; j < cn; j++) {
            acc += wl[j * H + h2] * hbuf[(size_t)srcl[j] * M + tid];
        }
    }
    __syncthreads();
    red[tid] = wsum; __syncthreads();
    for (int off = M / 2; off >= H; off >>= 1) {
        if (tid < off) red[tid] += red[tid + off];
        __syncthreads();
    }
    if (tid < H) sws[tid] = red[tid];
    __syncthreads();

    float o = acc / sws[h2] + bias[tid];
    out[(size_t)n * M + tid] = fmaxf(o, 0.f);
}

// ================= global mean pool: segmented (batch is sorted) =================
__global__ void k_ghist(const int* __restrict__ batch, int* __restrict__ gcount) {
    int n = blockIdx.x * 256 + threadIdx.x;
    if (n < NN) atomicAdd(&gcount[batch[n]], 1);
}

__global__ void k_gscan(const int* __restrict__ gcount, int* __restrict__ gstart) {
    int t = threadIdx.x;          // 64 threads (one wave)
    int s = gcount[t];
    for (int off = 1; off < 64; off <<= 1) {
        int u = __shfl_up(s, off);
        if (t >= off) s += u;
    }
    gstart[t + 1] = s;
    if (t == 0) gstart[0] = 0;
}

__global__ __launch_bounds__(256) void k_pool2(const float* __restrict__ feat,
                                               const int* __restrict__ gstart,
                                               float* __restrict__ pooled) {
    const int g = blockIdx.x;
    const int d = threadIdx.x & 63;
    const int c = threadIdx.x >> 6;   // 0..3
    const int s = gstart[g], e = gstart[g + 1];
    float acc = 0.f;
    for (int n = s + c; n < e; n += 4) acc += feat[(size_t)n * 64 + d];
    __shared__ float red[256];
    red[threadIdx.x] = acc; __syncthreads();
    if (c == 0) {
        float v = red[d] + red[64 + d] + red[128 + d] + red[192 + d];
        pooled[g * 64 + d] = v / fmaxf((float)(e - s), 1.f);   // mean (guard empty graph)
    }
}

// ================= actor/critic heads =================
__global__ void k_head1(const float* __restrict__ pooled,
                        const float* __restrict__ Wa1, const float* __restrict__ ba1,
                        const float* __restrict__ Wc1, const float* __restrict__ bc1,
                        float* __restrict__ a1, float* __restrict__ c1) {
    __shared__ float p[64];
    int g = blockIdx.x, t = threadIdx.x;
    if (t < 64) p[t] = pooled[g * 64 + t];
    __syncthreads();
    int j = t & 63;
    const float* W  = (t < 64) ? Wa1 : Wc1;
    const float* bb = (t < 64) ? ba1 : bc1;
    float acc = 0.f;
#pragma unroll 8
    for (int k = 0; k < 64; k++) acc += p[k] * W[k * 64 + j];
    acc = fmaxf(acc + bb[j], 0.f);
    if (t < 64) a1[g * 64 + j] = acc; else c1[g * 64 + j] = acc;
}

// FP32 OUTPUT — the reference returns float32, so d_out is float*
__global__ __launch_bounds__(1024) void k_head2(const float* __restrict__ a1, const float* __restrict__ c1,
                        const float* __restrict__ Wa2, const float* __restrict__ ba2,
                        const float* __restrict__ Wc2, const float* __restrict__ bc2,
                        float* __restrict__ out) {
    __shared__ float a[64], cc[64];
    int g = blockIdx.x, j = threadIdx.x;
    if (j < 64) a[j] = a1[g * 64 + j];
    else if (j < 128) cc[j - 64] = c1[g * 64 + (j - 64)];
    __syncthreads();
    float acc = 0.f;
#pragma unroll 8
    for (int k = 0; k < 64; k++) acc += a[k] * Wa2[k * AOUT + j];
    out[g * AOUT + j] = tanhf(acc + ba2[j]);
    if (j == 0) {
        float v = 0.f;
        for (int k = 0; k < 64; k++) v += cc[k] * Wc2[k];
        out[BG * AOUT + g] = v + bc2[0];
    }
}

extern "C" void kernel_launch(void* const* d_in, const int* in_sizes, int n_in,
                              void* d_out, int out_size, void* d_ws, size_t ws_size,
                              hipStream_t stream) {
    float* out = (float*)d_out;

    char* w = (char*)d_ws;
    auto alloc = [&](size_t bytes) { void* p = (void*)w; w += (bytes + 255) & ~size_t(255); return p; };
    float* xf      = (float*)alloc((size_t)NN * 128 * 4);
    float* wf      = (float*)alloc((size_t)WTOT * 4);
    int*   ei32    = (int*)alloc((size_t)2 * EE * 4);
    int*   b32     = (int*)alloc((size_t)NN * 4);
    float* bufA    = (float*)alloc((size_t)NN * 256 * 4);
    float* bufB    = (float*)alloc((size_t)NN * 256 * 4);
    float* sb      = (float*)alloc((size_t)NN * 4 * 4);
    float* db      = (float*)alloc((size_t)NN * 4 * 4);
    int*   deg     = (int*)alloc((size_t)NN * 4);
    int*   rowstart= (int*)alloc((size_t)(NN + 1) * 4);
    int*   cursor  = (int*)alloc((size_t)NN * 4);
    int*   ssrc    = (int*)alloc((size_t)EALL * 4);
    int*   gcount  = (int*)alloc((size_t)BG * 4);
    int*   gstart  = (int*)alloc((size_t)(BG + 1) * 4);
    float* pooled  = (float*)alloc((size_t)BG * 64 * 4);
    float* a1      = (float*)alloc((size_t)BG * 64 * 4);
    float* c1      = (float*)alloc((size_t)BG * 64 * 4);
    int*   flags   = (int*)alloc(64);

    // ---- detect dtypes + normalize inputs ----
    k_zero_i<<<1, 64, 0, stream>>>(flags, 4);
    k_detect_f<<<(NN * 128 + 255) / 256, 256, 0, stream>>>((const unsigned short*)d_in[0], NN * 128, &flags[2], &flags[3]);
    k_detect_i<<<(EE + 255) / 256, 256, 0, stream>>>((const unsigned int*)d_in[1], EE, &flags[1]);
    k_decide<<<1, 1, 0, stream>>>(flags);
    k_cvt_f<<<(NN * 128 + 255) / 256, 256, 0, stream>>>(d_in[0], xf, NN * 128, &flags[0]);
    WPtrs wp;
    for (int s = 0; s < 20; s++) wp.p[s] = d_in[3 + s];
    k_cvt_weights<<<(WTOT + 255) / 256, 256, 0, stream>>>(wp, wf, &flags[0]);
    k_cvt_i<<<(2 * EE + 255) / 256, 256, 0, stream>>>(d_in[1], ei32, 2 * EE, &flags[1]);
    k_cvt_i<<<(NN + 255) / 256, 256, 0, stream>>>(d_in[2], b32, NN, &flags[1]);

    const int wsz[20] = {32768,256,256,256,65536,256,256,256,16384,64,64,64,4096,64,65536,1024,4096,64,64,1};
    int woff[20]; int acc = 0;
    for (int s = 0; s < 20; s++) { woff[s] = acc; acc += wsz[s]; }
    const float *W1f = wf + woff[0], *as1f = wf + woff[1], *ad1f = wf + woff[2], *b1f = wf + woff[3];
    const float *W2f = wf + woff[4], *as2f = wf + woff[5], *ad2f = wf + woff[6], *b2f = wf + woff[7];
    const float *W3f = wf + woff[8], *as3f = wf + woff[9], *ad3f = wf + woff[10], *b3f = wf + woff[11];
    const float *Wa1f = wf + woff[12], *ba1f = wf + woff[13], *Wa2f = wf + woff[14], *ba2f = wf + woff[15];
    const float *Wc1f = wf + woff[16], *bc1f = wf + woff[17], *Wc2f = wf + woff[18], *bc2f = wf + woff[19];

    // ---- CSR build (shared across the 3 layers) ----
    k_zero_i<<<(NN + 255) / 256, 256, 0, stream>>>(deg, NN);
    k_hist<<<(EALL + 255) / 256, 256, 0, stream>>>(ei32, deg);
    k_scan<<<1, 1024, 0, stream>>>(deg, rowstart, cursor);
    k_scatter<<<(EALL + 255) / 256, 256, 0, stream>>>(ei32, cursor, ssrc);

    // ---- graph boundaries for pooling (batch is sorted) ----
    k_zero_i<<<1, 64, 0, stream>>>(gcount, BG);
    k_ghist<<<(NN + 255) / 256, 256, 0, stream>>>(b32, gcount);
    k_gscan<<<1, 64, 0, stream>>>(gcount, gstart);

    // ---- Layer 1: in 128, heads=4, out 64, concat ----
    k_gemm<128, 256><<<dim3(157, 4), 256, 0, stream>>>(xf, W1f, bufA);
    k_sd<4><<<NN, 256, 0, stream>>>(bufA, as1f, ad1f, sb, db);
    k_agg<4><<<NN, 256, 0, stream>>>(bufA, sb, db, rowstart, ssrc, b1f, bufB);

    // ---- Layer 2: in 256, heads=4, out 64, concat ----
    k_gemm<256, 256><<<dim3(157, 4), 256, 0, stream>>>(bufB, W2f, bufA);
    k_sd<4><<<NN, 256, 0, stream>>>(bufA, as2f, ad2f, sb, db);
    k_agg<4><<<NN, 256, 0, stream>>>(bufA, sb, db, rowstart, ssrc, b2f, bufB);

    // ---- Layer 3: in 256, heads=1, out 64 ----
    k_gemm<256, 64><<<dim3(157, 1), 256, 0, stream>>>(bufB, W3f, bufA);
    k_sd<1><<<(NN + 3) / 4, 256, 0, stream>>>(bufA, as3f, ad3f, sb, db);
    k_agg<1><<<NN, 64, 0, stream>>>(bufA, sb, db, rowstart, ssrc, b3f, bufB);

    // ---- global mean pool (segmented, no atomics) ----
    k_pool2<<<BG, 256, 0, stream>>>(bufB, gstart, pooled);

    // ---- heads ----
    k_head1<<<BG, 128, 0, stream>>>(pooled, Wa1f, ba1f, Wc1f, bc1f, a1, c1);
    k_head2<<<BG, 1024, 0, stream>>>(a1, c1, Wa2f, ba2f, Wc2f, bc2f, out);
}

// Round 8
// 445.921 us; speedup vs baseline: 1.4432x; 1.1811x over previous
//
#include <hip/hip_runtime.h>
#include <hip/hip_bf16.h>

#define NN 10000
#define EE 320000
#define EALL (EE + NN)   // 330000 edges incl. self loops
#define BG 64
#define AOUT 1024

#define NX (NN * 128)      // 1,280,000 x elements
#define WTOT 191361        // packed weight elements
#define NSF 262144         // sampled 16-bit halves for float-dtype probe
#define NSI 131072         // sampled index pairs for int-dtype probe

typedef __hip_bfloat16 bf16;

// ================= zero (deg | gcount | flags contiguous) =================
__global__ void k_zero_i(int* p, int n) { int i = blockIdx.x * 256 + threadIdx.x; if (i < n) p[i] = 0; }

// ================= fused dtype detection (sampled, wave-reduced) =================
// flags: [0] float dtype (1=fp32, 0=bf16); [1] int dtype (1=int32, 0=int64)
//        [2] nan-pattern count; [3] zero-even-half count
__global__ void k_detect(const unsigned short* __restrict__ x, const unsigned int* __restrict__ ei,
                         int* __restrict__ flags) {
    int i = blockIdx.x * 256 + threadIdx.x;
    bool nanp = false, zp = false, odd = false;
    if (i < NSF) {
        unsigned short h = x[i];
        nanp = (h & 0x7F80u) == 0x7F80u;       // bf16 inf/nan exponent pattern
        zp = ((i & 1) == 0) && (h == 0);       // zero low-mantissa half (fp32 storage of bf16-ish vals)
    } else if (i < NSF + NSI) {
        int j = i - NSF;
        odd = ei[2 * j + 1] != 0u;             // int64 high halves are all zero
    }
    unsigned long long bn = __ballot(nanp);
    unsigned long long bz = __ballot(zp);
    unsigned long long bo = __ballot(odd);
    if ((threadIdx.x & 63) == 0) {
        if (bn) atomicAdd(&flags[2], __popcll(bn));
        if (bz) atomicAdd(&flags[3], __popcll(bz));
        if (bo) atomicOr(&flags[1], 1);        // one atomic per wave max
    }
}

__global__ void k_decide(int* flags) {
    // fp32 storage if nan-pattern halves present (fp32 randn) or nearly all even halves zero
    flags[0] = (flags[2] > 0 || flags[3] > 50000) ? 1 : 0;
}

// ================= fused input conversion: x + weights + edge_index + batch =================
struct WPtrs { const void* p[20]; };
__global__ void k_cvt_all(const void* __restrict__ xsrc, WPtrs wp,
                          const void* __restrict__ eisrc, const void* __restrict__ bsrc,
                          float* __restrict__ xf, float* __restrict__ wf,
                          int* __restrict__ ei32, int* __restrict__ b32,
                          const int* __restrict__ flags) {
    const int sz[20] = {32768,256,256,256,65536,256,256,256,16384,64,64,64,4096,64,65536,1024,4096,64,64,1};
    int i = blockIdx.x * 256 + threadIdx.x;
    const int ff = flags[0], fi = flags[1];
    if (i < NX) {
        xf[i] = ff ? ((const float*)xsrc)[i] : __bfloat162float(((const bf16*)xsrc)[i]);
    } else if (i < NX + WTOT) {
        int j = i - NX;
        int seg = 0, off = 0;
        while (j - off >= sz[seg]) { off += sz[seg]; seg++; }
        const void* src = wp.p[seg];
        int k = j - off;
        wf[j] = ff ? ((const float*)src)[k] : __bfloat162float(((const bf16*)src)[k]);
    } else if (i < NX + WTOT + 2 * EE) {
        int j = i - NX - WTOT;
        ei32[j] = fi ? ((const int*)eisrc)[j] : (int)((const long long*)eisrc)[j];
    } else if (i < NX + WTOT + 2 * EE + NN) {
        int j = i - NX - WTOT - 2 * EE;
        b32[j] = fi ? ((const int*)bsrc)[j] : (int)((const long long*)bsrc)[j];
    }
}

// ================= fused histograms: edge degree + graph counts =================
__global__ void k_hist2(const int* __restrict__ ei, const int* __restrict__ batch,
                        int* __restrict__ deg, int* __restrict__ gcount) {
    int e = blockIdx.x * 256 + threadIdx.x;
    if (e < EALL) {
        int dst = (e < EE) ? ei[EE + e] : (e - EE);
        atomicAdd(&deg[dst], 1);
    }
    if (e < NN) atomicAdd(&gcount[batch[e]], 1);
}

// ================= fused scans: CSR rowstart + graph gstart =================
__global__ void k_scan2(const int* __restrict__ deg, int* __restrict__ rowstart, int* __restrict__ cursor,
                        const int* __restrict__ gcount, int* __restrict__ gstart) {
    __shared__ int part[1024];
    const int t = threadIdx.x;
    if (t < 64) {   // wave 0: graph-boundary scan
        int s = gcount[t];
        for (int off = 1; off < 64; off <<= 1) {
            int u = __shfl_up(s, off);
            if (t >= off) s += u;
        }
        gstart[t + 1] = s;
        if (t == 0) gstart[0] = 0;
    }
    const int base = t * 10;
    int local[10];
    int s = 0;
    for (int i = 0; i < 10; i++) {
        int idx = base + i;
        int v = (idx < NN) ? deg[idx] : 0;
        local[i] = s; s += v;
    }
    part[t] = s; __syncthreads();
    for (int off = 1; off < 1024; off <<= 1) {
        int v = (t >= off) ? part[t - off] : 0;
        __syncthreads();
        part[t] += v;
        __syncthreads();
    }
    int pre = (t == 0) ? 0 : part[t - 1];
    for (int i = 0; i < 10; i++) {
        int idx = base + i;
        if (idx < NN) { int v = pre + local[i]; rowstart[idx] = v; cursor[idx] = v; }
    }
    if (t == 1023) rowstart[NN] = part[1023];
}

__global__ void k_scatter(const int* __restrict__ ei, int* __restrict__ cursor, int* __restrict__ ssrc) {
    int e = blockIdx.x * 256 + threadIdx.x;
    if (e >= EALL) return;
    int src, dst;
    if (e < EE) { src = ei[e]; dst = ei[EE + e]; }
    else { src = e - EE; dst = src; }
    int pos = atomicAdd(&cursor[dst], 1);
    ssrc[pos] = src;
}

// ================= GEMM: C[N,M] = A[N,K] @ W[K,M], 64x64 tile, 4x4/thread =================
template<int K, int M>
__global__ __launch_bounds__(256) void k_gemm(const float* __restrict__ A, const float* __restrict__ W,
                                              float* __restrict__ C) {
    constexpr int BK = 32;
    __shared__ float At[BK][68];
    __shared__ float Wt[BK][64];
    const int row0 = blockIdx.x * 64;
    const int col0 = blockIdx.y * 64;
    const int t = threadIdx.x;
    const int tx = t & 15, ty = t >> 4;
    float acc[4][4] = {};

    for (int k0 = 0; k0 < K; k0 += BK) {
        {
            const int kk = t & 31;
            const int rbase = t >> 5;
#pragma unroll
            for (int j = 0; j < 8; j++) {
                int r = rbase + j * 8;
                int row = row0 + r;
                At[kk][r] = (row < NN) ? A[(size_t)row * K + k0 + kk] : 0.f;
            }
            const int cc = t & 63;
            const int kbase = t >> 6;
#pragma unroll
            for (int j = 0; j < 8; j++) {
                int kk2 = kbase + j * 4;
                Wt[kk2][cc] = W[(size_t)(k0 + kk2) * M + col0 + cc];
            }
        }
        __syncthreads();
#pragma unroll
        for (int k = 0; k < BK; k++) {
            float4 a4 = *(const float4*)&At[k][ty * 4];
            float4 w4 = *(const float4*)&Wt[k][tx * 4];
            float av[4] = {a4.x, a4.y, a4.z, a4.w};
            float wv[4] = {w4.x, w4.y, w4.z, w4.w};
#pragma unroll
            for (int m = 0; m < 4; m++)
#pragma unroll
                for (int n = 0; n < 4; n++)
                    acc[m][n] += av[m] * wv[n];
        }
        __syncthreads();
    }
#pragma unroll
    for (int m = 0; m < 4; m++) {
        int row = row0 + ty * 4 + m;
        if (row < NN) {
            float4 v = make_float4(acc[m][0], acc[m][1], acc[m][2], acc[m][3]);
            *(float4*)&C[(size_t)row * M + col0 + tx * 4] = v;
        }
    }
}

// ================= attention terms s,d: one wave per (n,h) =================
template<int H>
__global__ void k_sd(const float* __restrict__ h, const float* __restrict__ asrc,
                     const float* __restrict__ adst, float* __restrict__ sb, float* __restrict__ db) {
    int gw = (blockIdx.x * blockDim.x + threadIdx.x) >> 6;
    int lane = threadIdx.x & 63;
    int n = gw / H, hh = gw - n * H;
    if (n >= NN) return;
    float v = h[(size_t)(n * H + hh) * 64 + lane];
    float ss = v * asrc[hh * 64 + lane];
    float dd = v * adst[hh * 64 + lane];
#pragma unroll
    for (int off = 32; off > 0; off >>= 1) {
        ss += __shfl_down(ss, off);
        dd += __shfl_down(dd, off);
    }
    if (lane == 0) { sb[n * H + hh] = ss; db[n * H + hh] = dd; }
}

// ================= softmax + aggregate per dst node (one block per node) =================
template<int H>
__global__ void k_agg(const float* __restrict__ hbuf, const float* __restrict__ sb,
                      const float* __restrict__ db, const int* __restrict__ rowstart,
                      const int* __restrict__ ssrc, const float* __restrict__ bias,
                      float* __restrict__ out) {
    constexpr int M = H * 64;
    constexpr int LH = (H == 4) ? 2 : 0;
    const int n = blockIdx.x;
    const int tid = threadIdx.x;
    const int start = rowstart[n], end = rowstart[n + 1];
    const int slot = tid >> LH;
    const int hh = tid & (H - 1);
    const int h2 = tid >> 6;
    __shared__ float red[M];
    __shared__ float sm[H], sws[H];
    __shared__ float wl[64 * H];
    __shared__ int srcl[64];
    const float dn = db[n * H + hh];

    float mymax = -3e38f;
    for (int p = start + slot; p < end; p += 64) {
        float e = sb[ssrc[p] * H + hh] + dn;
        e = e > 0.f ? e : 0.2f * e;
        mymax = fmaxf(mymax, e);
    }
    red[tid] = mymax; __syncthreads();
    for (int off = M / 2; off >= H; off >>= 1) {
        if (tid < off) red[tid] = fmaxf(red[tid], red[tid + off]);
        __syncthreads();
    }
    if (tid < H) sm[tid] = red[tid];
    __syncthreads();
    const float mh = sm[hh];

    float wsum = 0.f;
    float acc = 0.f;
    for (int c = start; c < end; c += 64) {
        const int cn = min(64, end - c);
        __syncthreads();
        if (slot < cn) {
            int s = ssrc[c + slot];
            float e = sb[s * H + hh] + dn;
            e = e > 0.f ? e : 0.2f * e;
            float wv = __expf(e - mh);
            wl[slot * H + hh] = wv;
            wsum += wv;
            if (hh == 0) srcl[slot] = s;
        }
        __syncthreads();
        for (int j = 0; j < cn; j++) {
            acc += wl[j * H + h2] * hbuf[(size_t)srcl[j] * M + tid];
        }
    }
    __syncthreads();
    red[tid] = wsum; __syncthreads();
    for (int off = M / 2; off >= H; off >>= 1) {
        if (tid < off) red[tid] += red[tid + off];
        __syncthreads();
    }
    if (tid < H) sws[tid] = red[tid];
    __syncthreads();

    float o = acc / sws[h2] + bias[tid];
    out[(size_t)n * M + tid] = fmaxf(o, 0.f);
}

// ================= global mean pool: segmented (batch is sorted) =================
__global__ __launch_bounds__(256) void k_pool2(const float* __restrict__ feat,
                                               const int* __restrict__ gstart,
                                               float* __restrict__ pooled) {
    const int g = blockIdx.x;
    const int d = threadIdx.x & 63;
    const int c = threadIdx.x >> 6;
    const int s = gstart[g], e = gstart[g + 1];
    float acc = 0.f;
    for (int n = s + c; n < e; n += 4) acc += feat[(size_t)n * 64 + d];
    __shared__ float red[256];
    red[threadIdx.x] = acc; __syncthreads();
    if (c == 0) {
        float v = red[d] + red[64 + d] + red[128 + d] + red[192 + d];
        pooled[g * 64 + d] = v / fmaxf((float)(e - s), 1.f);
    }
}

// ================= actor/critic heads =================
__global__ void k_head1(const float* __restrict__ pooled,
                        const float* __restrict__ Wa1, const float* __restrict__ ba1,
                        const float* __restrict__ Wc1, const float* __restrict__ bc1,
                        float* __restrict__ a1, float* __restrict__ c1) {
    __shared__ float p[64];
    int g = blockIdx.x, t = threadIdx.x;
    if (t < 64) p[t] = pooled[g * 64 + t];
    __syncthreads();
    int j = t & 63;
    const float* W  = (t < 64) ? Wa1 : Wc1;
    const float* bb = (t < 64) ? ba1 : bc1;
    float acc = 0.f;
#pragma unroll 8
    for (int k = 0; k < 64; k++) acc += p[k] * W[k * 64 + j];
    acc = fmaxf(acc + bb[j], 0.f);
    if (t < 64) a1[g * 64 + j] = acc; else c1[g * 64 + j] = acc;
}

// FP32 OUTPUT — the reference returns float32, so d_out is float*
__global__ __launch_bounds__(1024) void k_head2(const float* __restrict__ a1, const float* __restrict__ c1,
                        const float* __restrict__ Wa2, const float* __restrict__ ba2,
                        const float* __restrict__ Wc2, const float* __restrict__ bc2,
                        float* __restrict__ out) {
    __shared__ float a[64], cc[64];
    int g = blockIdx.x, j = threadIdx.x;
    if (j < 64) a[j] = a1[g * 64 + j];
    else if (j < 128) cc[j - 64] = c1[g * 64 + (j - 64)];
    __syncthreads();
    float acc = 0.f;
#pragma unroll 8
    for (int k = 0; k < 64; k++) acc += a[k] * Wa2[k * AOUT + j];
    out[g * AOUT + j] = tanhf(acc + ba2[j]);
    if (j == 0) {
        float v = 0.f;
        for (int k = 0; k < 64; k++) v += cc[k] * Wc2[k];
        out[BG * AOUT + g] = v + bc2[0];
    }
}

extern "C" void kernel_launch(void* const* d_in, const int* in_sizes, int n_in,
                              void* d_out, int out_size, void* d_ws, size_t ws_size,
                              hipStream_t stream) {
    float* out = (float*)d_out;

    char* w = (char*)d_ws;
    auto alloc = [&](size_t bytes) { void* p = (void*)w; w += (bytes + 255) & ~size_t(255); return p; };
    float* xf      = (float*)alloc((size_t)NX * 4);
    float* wf      = (float*)alloc((size_t)WTOT * 4);
    int*   ei32    = (int*)alloc((size_t)2 * EE * 4);
    int*   b32     = (int*)alloc((size_t)NN * 4);
    float* bufA    = (float*)alloc((size_t)NN * 256 * 4);
    float* bufB    = (float*)alloc((size_t)NN * 256 * 4);
    float* sb      = (float*)alloc((size_t)NN * 4 * 4);
    float* db      = (float*)alloc((size_t)NN * 4 * 4);
    // deg | gcount | flags contiguous for one-shot zeroing
    int*   deg     = (int*)alloc((size_t)(NN + BG + 16) * 4);
    int*   gcount  = deg + NN;
    int*   flags   = deg + NN + BG;
    int*   rowstart= (int*)alloc((size_t)(NN + 1) * 4);
    int*   cursor  = (int*)alloc((size_t)NN * 4);
    int*   ssrc    = (int*)alloc((size_t)EALL * 4);
    int*   gstart  = (int*)alloc((size_t)(BG + 1) * 4);
    float* pooled  = (float*)alloc((size_t)BG * 64 * 4);
    float* a1      = (float*)alloc((size_t)BG * 64 * 4);
    float* c1      = (float*)alloc((size_t)BG * 64 * 4);

    // ---- zero deg+gcount+flags in one launch ----
    k_zero_i<<<(NN + BG + 16 + 255) / 256, 256, 0, stream>>>(deg, NN + BG + 16);

    // ---- fused dtype detection (sampled, wave-reduced atomics) ----
    k_detect<<<(NSF + NSI + 255) / 256, 256, 0, stream>>>(
        (const unsigned short*)d_in[0], (const unsigned int*)d_in[1], flags);
    k_decide<<<1, 1, 0, stream>>>(flags);

    // ---- fused input conversion ----
    WPtrs wp;
    for (int s = 0; s < 20; s++) wp.p[s] = d_in[3 + s];
    k_cvt_all<<<(NX + WTOT + 2 * EE + NN + 255) / 256, 256, 0, stream>>>(
        d_in[0], wp, d_in[1], d_in[2], xf, wf, ei32, b32, flags);

    const int wsz[20] = {32768,256,256,256,65536,256,256,256,16384,64,64,64,4096,64,65536,1024,4096,64,64,1};
    int woff[20]; int acc = 0;
    for (int s = 0; s < 20; s++) { woff[s] = acc; acc += wsz[s]; }
    const float *W1f = wf + woff[0], *as1f = wf + woff[1], *ad1f = wf + woff[2], *b1f = wf + woff[3];
    const float *W2f = wf + woff[4], *as2f = wf + woff[5], *ad2f = wf + woff[6], *b2f = wf + woff[7];
    const float *W3f = wf + woff[8], *as3f = wf + woff[9], *ad3f = wf + woff[10], *b3f = wf + woff[11];
    const float *Wa1f = wf + woff[12], *ba1f = wf + woff[13], *Wa2f = wf + woff[14], *ba2f = wf + woff[15];
    const float *Wc1f = wf + woff[16], *bc1f = wf + woff[17], *Wc2f = wf + woff[18], *bc2f = wf + woff[19];

    // ---- CSR + graph boundaries ----
    k_hist2<<<(EALL + 255) / 256, 256, 0, stream>>>(ei32, b32, deg, gcount);
    k_scan2<<<1, 1024, 0, stream>>>(deg, rowstart, cursor, gcount, gstart);
    k_scatter<<<(EALL + 255) / 256, 256, 0, stream>>>(ei32, cursor, ssrc);

    // ---- Layer 1: in 128, heads=4, out 64, concat ----
    k_gemm<128, 256><<<dim3(157, 4), 256, 0, stream>>>(xf, W1f, bufA);
    k_sd<4><<<NN, 256, 0, stream>>>(bufA, as1f, ad1f, sb, db);
    k_agg<4><<<NN, 256, 0, stream>>>(bufA, sb, db, rowstart, ssrc, b1f, bufB);

    // ---- Layer 2: in 256, heads=4, out 64, concat ----
    k_gemm<256, 256><<<dim3(157, 4), 256, 0, stream>>>(bufB, W2f, bufA);
    k_sd<4><<<NN, 256, 0, stream>>>(bufA, as2f, ad2f, sb, db);
    k_agg<4><<<NN, 256, 0, stream>>>(bufA, sb, db, rowstart, ssrc, b2f, bufB);

    // ---- Layer 3: in 256, heads=1, out 64 ----
    k_gemm<256, 64><<<dim3(157, 1), 256, 0, stream>>>(bufB, W3f, bufA);
    k_sd<1><<<(NN + 3) / 4, 256, 0, stream>>>(bufA, as3f, ad3f, sb, db);
    k_agg<1><<<NN, 64, 0, stream>>>(bufA, sb, db, rowstart, ssrc, b3f, bufB);

    // ---- global mean pool (segmented, no atomics) ----
    k_pool2<<<BG, 256, 0, stream>>>(bufB, gstart, pooled);

    // ---- heads ----
    k_head1<<<BG, 128, 0, stream>>>(pooled, Wa1f, ba1f, Wc1f, bc1f, a1, c1);
    k_head2<<<BG, 1024, 0, stream>>>(a1, c1, Wa2f, ba2f, Wc2f, bc2f, out);
}